// Round 5
// baseline (358.326 us; speedup 1.0000x reference)
//
#include <hip/hip_runtime.h>
#include <hip/hip_cooperative_groups.h>
#include <math.h>

namespace cg = cooperative_groups;

#define B_  128
#define E_  128
#define H2_ 512
#define H3_ 1536
#define L_  512
#define V_  50000
#define VL_ 50512   // V + L

typedef short bf16x8 __attribute__((ext_vector_type(8)));
typedef float f32x4 __attribute__((ext_vector_type(4)));

__device__ __forceinline__ float fast_tanh(float x) {
    float e = __expf(2.f * x);
    return 1.f - 2.f / (e + 1.f);
}
__device__ __forceinline__ float fast_sigmoid(float x) {
    return 1.f / (1.f + __expf(-x));
}
__device__ __forceinline__ short f2bf(float f) {
    unsigned u = __float_as_uint(f);
    u += 0x7fff + ((u >> 16) & 1);        // RNE
    return (short)(u >> 16);
}

// ---------------- init: bias-broadcast split-K targets, zero pad/rsum ----------------
// [0,196608) gx=b_ih | [196608,393216) gh=b_hh | [393216,458752) dsl=b_ds |
// [458752,475136) hid=b_oh | [475136,540672) out pad=0 | [540672,540800) rsum=0
__global__ void k_init(float* __restrict__ gx, float* __restrict__ gh,
                       float* __restrict__ dsl, float* __restrict__ hid,
                       float* __restrict__ out, float* __restrict__ rsum,
                       const float* __restrict__ b_ih, const float* __restrict__ b_hh,
                       const float* __restrict__ b_ds, const float* __restrict__ b_oh) {
    int i = blockIdx.x * blockDim.x + threadIdx.x;
    if (i < 196608) { gx[i] = b_ih[i % 1536]; return; }
    i -= 196608;
    if (i < 196608) { gh[i] = b_hh[i % 1536]; return; }
    i -= 196608;
    if (i < 65536)  { dsl[i] = b_ds[i & 511]; return; }
    i -= 65536;
    if (i < 16384)  { hid[i] = b_oh[i & 127]; return; }
    i -= 16384;
    if (i < 65536)  { out[(size_t)(i >> 9) * VL_ + V_ + (i & 511)] = 0.f; return; }
    i -= 65536;
    if (i < 128)    rsum[i] = 0.f;
}

// ---------------- gx & gh GEMMs, split-K, one kernel (z: 0-1 gx, 2-5 gh) -------------
// atomicAdd into bias-pre-initialized outputs
__global__ void k_gates(const int* __restrict__ ids, const float* __restrict__ tab,
                        const float* __restrict__ hidden,
                        const float* __restrict__ W_ih, const float* __restrict__ W_hh,
                        float* __restrict__ gx, float* __restrict__ gh) {
    __shared__ float As[32][36];
    __shared__ float Ws[32][36];
    int z = blockIdx.z;
    int which = (z < 2) ? 0 : 1;
    int kbeg  = which ? (z - 2) * 128 : z * 64;
    int kiter = which ? 4 : 2;                      // BK=32 iterations
    const float* W = which ? W_hh : W_ih;
    int ldw = which ? H2_ : E_;
    float* C = which ? gh : gx;
    int bm = blockIdx.x * 32, bn = blockIdx.y * 32;
    int tid = threadIdx.x;
    int tm0 = (tid / 16) * 2, tn0 = (tid % 16) * 2;
    float acc[2][2] = {};
    for (int it = 0; it < kiter; ++it) {
        int k0 = kbeg + it * 32;
        // A tile 32x32
        for (int v = tid; v < 256; v += 256) {
            int m = v >> 3, q = (v & 7) << 2;
            int gm = bm + m;
            const float* arow = which ? (hidden + (size_t)gm * H2_)
                                      : (tab + (size_t)ids[gm] * E_);
            float4 x = *(const float4*)(arow + k0 + q);
            As[q+0][m] = x.x; As[q+1][m] = x.y; As[q+2][m] = x.z; As[q+3][m] = x.w;
        }
        // W tile 32x32
        for (int v = tid; v < 256; v += 256) {
            int n = v >> 3, q = (v & 7) << 2;
            float4 x = *(const float4*)(W + (size_t)(bn + n) * ldw + k0 + q);
            Ws[q+0][n] = x.x; Ws[q+1][n] = x.y; Ws[q+2][n] = x.z; Ws[q+3][n] = x.w;
        }
        __syncthreads();
        #pragma unroll
        for (int kk = 0; kk < 32; ++kk) {
            float a0 = As[kk][tm0], a1 = As[kk][tm0+1];
            float w0 = Ws[kk][tn0], w1 = Ws[kk][tn0+1];
            acc[0][0] += a0*w0; acc[0][1] += a0*w1;
            acc[1][0] += a1*w0; acc[1][1] += a1*w1;
        }
        __syncthreads();
    }
    #pragma unroll
    for (int i = 0; i < 2; ++i)
        #pragma unroll
        for (int j = 0; j < 2; ++j)
            atomicAdd(&C[(size_t)(bm+tm0+i) * H3_ + bn+tn0+j], acc[i][j]);
}

// ---------------- generic tiled GEMM (kept for dsl/hid), split-K atomic ----------------
template<int BM, int BN, int BK, int TM, int TN, int SPLITK>
__global__ void gemm_t(const float* __restrict__ A, int lda,
                       const float* __restrict__ W, int ldw,
                       float* __restrict__ C, int ldc,
                       int N, int K) {
    __shared__ float As[BK][BM + 4];
    __shared__ float Ws[BK][BN + 4];
    int bm = blockIdx.x * BM, bn = blockIdx.y * BN;
    int tid = threadIdx.x;
    constexpr int NT = BN / TN;
    int tm0 = (tid / NT) * TM;
    int tn0 = (tid % NT) * TN;
    int kchunk = K / SPLITK;
    int kbeg = blockIdx.z * kchunk;
    float acc[TM][TN] = {};
    for (int k0 = kbeg; k0 < kbeg + kchunk; k0 += BK) {
        #pragma unroll
        for (int v = tid; v < BM * BK / 4; v += 256) {
            int m = v / (BK / 4), q = (v % (BK / 4)) * 4;
            float4 x = *(const float4*)(A + (size_t)(bm + m) * lda + k0 + q);
            As[q+0][m] = x.x; As[q+1][m] = x.y; As[q+2][m] = x.z; As[q+3][m] = x.w;
        }
        #pragma unroll
        for (int v = tid; v < BN * BK / 4; v += 256) {
            int n = v / (BK / 4), q = (v % (BK / 4)) * 4;
            float4 x = *(const float4*)(W + (size_t)(bn + n) * ldw + k0 + q);
            Ws[q+0][n] = x.x; Ws[q+1][n] = x.y; Ws[q+2][n] = x.z; Ws[q+3][n] = x.w;
        }
        __syncthreads();
        #pragma unroll
        for (int kk = 0; kk < BK; ++kk) {
            float a[TM], w[TN];
            #pragma unroll
            for (int i = 0; i < TM; ++i) a[i] = As[kk][tm0 + i];
            #pragma unroll
            for (int j = 0; j < TN; ++j) w[j] = Ws[kk][tn0 + j];
            #pragma unroll
            for (int i = 0; i < TM; ++i)
                #pragma unroll
                for (int j = 0; j < TN; ++j) acc[i][j] += a[i] * w[j];
        }
        __syncthreads();
    }
    #pragma unroll
    for (int i = 0; i < TM; ++i)
        #pragma unroll
        for (int j = 0; j < TN; ++j)
            atomicAdd(&C[(size_t)(bm+tm0+i) * ldc + bn+tn0+j], acc[i][j]);
}

// ---------------- GRU gates (+ zero ctx region) ----------------
__global__ void k_gru(const float* __restrict__ gx, const float* __restrict__ gh,
                      const float* __restrict__ h0,
                      float* __restrict__ comb, float* __restrict__ hout) {
    int idx = blockIdx.x * blockDim.x + threadIdx.x;  // B*H2 = 65536
    int b = idx >> 9, h = idx & 511;
    const float* gxb = gx + b * H3_;
    const float* ghb = gh + b * H3_;
    float xr = gxb[h], xz = gxb[H2_ + h], xn = gxb[2 * H2_ + h];
    float hr = ghb[h], hz = ghb[H2_ + h], hn = ghb[2 * H2_ + h];
    float r = fast_sigmoid(xr + hr);
    float z = fast_sigmoid(xz + hz);
    float n = fast_tanh(xn + r * hn);
    float hv = (1.f - z) * n + z * h0[idx];
    comb[b * (2 * H2_) + h] = hv;
    comb[b * (2 * H2_) + H2_ + h] = 0.f;
    hout[idx] = hv;
}

// ---------------- attention scores: one wave per (l,b) ----------------
__global__ void k_scores(const float* __restrict__ enc, const float* __restrict__ dsl,
                         const float* __restrict__ w_h, const float* __restrict__ att_v,
                         float* __restrict__ scores) {
    int wid = (blockIdx.x << 2) + (threadIdx.x >> 6);
    int lane = threadIdx.x & 63;
    int l = wid >> 7, b = wid & 127;
    const float4* e4 = (const float4*)(enc + ((size_t)(l * B_ + b)) * H2_);
    const float4* d4 = (const float4*)(dsl + b * H2_);
    const float4* w4 = (const float4*)w_h;
    const float4* v4 = (const float4*)att_v;
    float s = 0.f;
    #pragma unroll
    for (int i = 0; i < 2; ++i) {
        int j = lane + (i << 6);
        float4 e = e4[j], d = d4[j], w = w4[j], v = v4[j];
        s += v.x * fast_tanh(w.x * e.x + d.x);
        s += v.y * fast_tanh(w.y * e.y + d.y);
        s += v.z * fast_tanh(w.z * e.z + d.z);
        s += v.w * fast_tanh(w.w * e.w + d.w);
    }
    #pragma unroll
    for (int o = 32; o; o >>= 1) s += __shfl_xor(s, o);
    if (lane == 0) scores[l * B_ + b] = s;
}

// ---------------- softmax over batch axis (per l) ----------------
__global__ void k_softmax(const float* __restrict__ scores, float* __restrict__ attn) {
    int l = blockIdx.x, lane = threadIdx.x;   // 64 threads
    float s0 = scores[l * B_ + lane], s1 = scores[l * B_ + lane + 64];
    float m = fmaxf(s0, s1);
    #pragma unroll
    for (int o = 32; o; o >>= 1) m = fmaxf(m, __shfl_xor(m, o));
    float e0 = __expf(s0 - m), e1 = __expf(s1 - m);
    float t = e0 + e1;
    #pragma unroll
    for (int o = 32; o; o >>= 1) t += __shfl_xor(t, o);
    float inv = 1.f / t;
    attn[l * B_ + lane] = e0 * inv;
    attn[l * B_ + lane + 64] = e1 * inv;
}

// ---------------- context: block (b, l-chunk of 64) ----------------
__global__ void k_context(const float* __restrict__ enc, const float* __restrict__ attn,
                          float* __restrict__ comb) {
    int b = blockIdx.x, h = threadIdx.x;
    int l0 = blockIdx.y << 6;
    __shared__ float a_s[64];
    if (threadIdx.x < 64) a_s[threadIdx.x] = attn[(l0 + threadIdx.x) * B_ + b];
    __syncthreads();
    const float* e = enc + ((size_t)l0 * B_ + b) * H2_ + h;
    float c = 0.f;
    #pragma unroll 8
    for (int i = 0; i < 64; ++i) c += a_s[i] * e[(size_t)i * B_ * H2_];
    atomicAdd(&comb[b * (2 * H2_) + H2_ + h], c);
}

// ---------------- p_gen: one wave per b ----------------
__global__ void k_pgen(const float* __restrict__ comb,
                       const int* __restrict__ ids, const float* __restrict__ tab,
                       const float* __restrict__ W_ptr, const float* __restrict__ b_ptr,
                       float* __restrict__ pgen) {
    int b = blockIdx.x, lane = threadIdx.x;  // 64 threads
    float s = 0.f;
    for (int j = lane; j < 2 * H2_; j += 64) s += W_ptr[j] * comb[b * (2 * H2_) + j];
    const float* erow = tab + (size_t)ids[b] * E_;
    for (int j = lane; j < E_; j += 64) s += W_ptr[2 * H2_ + j] * erow[j];
    #pragma unroll
    for (int o = 32; o; o >>= 1) s += __shfl_xor(s, o);
    if (lane == 0) pgen[b] = fast_sigmoid(s + b_ptr[0]);
}

// ---------------- cooperative: vocab MFMA GEMM + exp + rsum -> scale-write -> scatter --
// block: 256 thr (4 waves). Block covers all 128 rows x 128 cols. Grid 391.
// Wave w owns n-strip [blk*128 + w*32, +32) = two 16-wide n-tiles.
__global__ void k_vocab_coop(const float* __restrict__ hid, const float* __restrict__ Wov,
                             const float* __restrict__ bov, const float* __restrict__ pgen,
                             float* __restrict__ rsum, float* __restrict__ out,
                             const int* __restrict__ full_in, const float* __restrict__ attn) {
    int L = threadIdx.x & 63, w = threadIdx.x >> 6;
    int lrow = L & 15, lk = L >> 4;          // fragment lane decomposition
    int n0 = blockIdx.x * 128 + w * 32;

    // ---- load B fragments: Wov rows n0+nt*16+lrow, k = kk*32 + lk*8 + j ----
    bf16x8 bfr[2][4];
    #pragma unroll
    for (int nt = 0; nt < 2; ++nt) {
        int n = n0 + nt * 16 + lrow;
        #pragma unroll
        for (int kk = 0; kk < 4; ++kk) {
            bf16x8 f;
            if (n < V_) {
                const float* p = Wov + (size_t)n * 128 + kk * 32 + lk * 8;
                float4 x = *(const float4*)p, y = *(const float4*)(p + 4);
                f[0]=f2bf(x.x); f[1]=f2bf(x.y); f[2]=f2bf(x.z); f[3]=f2bf(x.w);
                f[4]=f2bf(y.x); f[5]=f2bf(y.y); f[6]=f2bf(y.z); f[7]=f2bf(y.w);
            } else {
                #pragma unroll
                for (int j = 0; j < 8; ++j) f[j] = 0;
            }
            bfr[nt][kk] = f;
        }
    }
    // ---- MFMA: 8 m-tiles x 2 n-tiles x 4 k-chunks ----
    f32x4 acc[8][2] = {};
    #pragma unroll
    for (int mt = 0; mt < 8; ++mt) {
        bf16x8 afr[4];
        #pragma unroll
        for (int kk = 0; kk < 4; ++kk) {
            const float* p = hid + (size_t)(mt * 16 + lrow) * 128 + kk * 32 + lk * 8;
            float4 x = *(const float4*)p, y = *(const float4*)(p + 4);
            bf16x8 f;
            f[0]=f2bf(x.x); f[1]=f2bf(x.y); f[2]=f2bf(x.z); f[3]=f2bf(x.w);
            f[4]=f2bf(y.x); f[5]=f2bf(y.y); f[6]=f2bf(y.z); f[7]=f2bf(y.w);
            afr[kk] = f;
        }
        #pragma unroll
        for (int nt = 0; nt < 2; ++nt)
            #pragma unroll
            for (int kk = 0; kk < 4; ++kk)
                acc[mt][nt] = __builtin_amdgcn_mfma_f32_16x16x32_bf16(
                    afr[kk], bfr[nt][kk], acc[mt][nt], 0, 0, 0);
    }
    // ---- exp epilogue in registers + per-row partial sums ----
    float bv[2];
    #pragma unroll
    for (int nt = 0; nt < 2; ++nt) {
        int n = n0 + nt * 16 + lrow;
        bv[nt] = (n < V_) ? bov[n] : 0.f;
    }
    float rs[8][4];
    #pragma unroll
    for (int mt = 0; mt < 8; ++mt) {
        #pragma unroll
        for (int r = 0; r < 4; ++r) rs[mt][r] = 0.f;
        #pragma unroll
        for (int nt = 0; nt < 2; ++nt) {
            int n = n0 + nt * 16 + lrow;
            if (n < V_) {
                #pragma unroll
                for (int r = 0; r < 4; ++r) {
                    float e = __expf(acc[mt][nt][r] + bv[nt]);
                    acc[mt][nt][r] = e;
                    rs[mt][r] += e;
                }
            }
        }
    }
    // reduce across the 16 lanes sharing each row (lanes differ in L&15)
    #pragma unroll
    for (int o = 1; o < 16; o <<= 1)
        #pragma unroll
        for (int mt = 0; mt < 8; ++mt)
            #pragma unroll
            for (int r = 0; r < 4; ++r) rs[mt][r] += __shfl_xor(rs[mt][r], o);
    if (lrow == 0) {
        #pragma unroll
        for (int mt = 0; mt < 8; ++mt)
            #pragma unroll
            for (int r = 0; r < 4; ++r)
                atomicAdd(&rsum[mt * 16 + lk * 4 + r], rs[mt][r]);
    }

    cg::this_grid().sync();

    // ---- scale from registers, single write ----
    #pragma unroll
    for (int mt = 0; mt < 8; ++mt) {
        #pragma unroll
        for (int r = 0; r < 4; ++r) {
            int row = mt * 16 + lk * 4 + r;
            float sc = pgen[row] / rsum[row];
            #pragma unroll
            for (int nt = 0; nt < 2; ++nt) {
                int n = n0 + nt * 16 + lrow;
                if (n < V_) out[(size_t)row * VL_ + n] = acc[mt][nt][r] * sc;
            }
        }
    }

    cg::this_grid().sync();

    // ---- scatter copy distribution (first 256 blocks, 1 elem/thread) ----
    if (blockIdx.x < 256) {
        int idx = blockIdx.x * 256 + threadIdx.x;   // L*B = 65536
        int b = idx & 127;
        int tok = full_in[idx];
        atomicAdd(&out[(size_t)b * VL_ + tok], (1.f - pgen[b]) * attn[idx]);
    }
}

extern "C" void kernel_launch(void* const* d_in, const int* in_sizes, int n_in,
                              void* d_out, int out_size, void* d_ws, size_t ws_size,
                              hipStream_t stream) {
    const int*   input_ids = (const int*)d_in[0];
    const float* hidden    = (const float*)d_in[1];
    const float* enc       = (const float*)d_in[2];
    const int*   full_in   = (const int*)d_in[3];
    const float* emb_tab   = (const float*)d_in[4];
    const float* W_ih      = (const float*)d_in[5];
    const float* W_hh      = (const float*)d_in[6];
    const float* b_ih      = (const float*)d_in[7];
    const float* b_hh      = (const float*)d_in[8];
    const float* W_ds      = (const float*)d_in[9];
    const float* b_ds      = (const float*)d_in[10];
    const float* w_h       = (const float*)d_in[11];
    const float* att_v     = (const float*)d_in[12];
    const float* W_oh      = (const float*)d_in[13];
    const float* b_oh      = (const float*)d_in[14];
    const float* W_ov      = (const float*)d_in[15];
    const float* b_ov      = (const float*)d_in[16];
    const float* W_ptr     = (const float*)d_in[17];
    const float* b_ptr     = (const float*)d_in[18];

    float* out = (float*)d_out;
    float* p_final = out;                                  // [B, VL]
    float* h_out   = out + (size_t)B_ * VL_;               // [B, H2]
    float* attn    = out + (size_t)B_ * VL_ + B_ * H2_;    // [L, B]

    float* ws = (float*)d_ws;
    float* gx     = ws;            // 196608
    float* gh     = gx + 196608;   // 196608
    float* comb   = gh + 196608;   // 131072  [B, 2*H2]: h_new | context
    float* dsl    = comb + 131072; // 65536
    float* scores = dsl + 65536;   // 65536
    float* hid    = scores + 65536;// 16384
    float* pgen   = hid + 16384;   // 128
    float* rsum   = pgen + 128;    // 128

    // 0. init bias targets / zero pad & rsum
    k_init<<<dim3(2113), dim3(256), 0, stream>>>(gx, gh, dsl, hid, out, rsum,
                                                 b_ih, b_hh, b_ds, b_oh);
    // 1. gx & gh GEMMs (split-K, atomic)
    k_gates<<<dim3(4,48,6), dim3(256), 0, stream>>>(input_ids, emb_tab, hidden,
                                                    W_ih, W_hh, gx, gh);
    // 2. GRU -> h_new (+ zero ctx region)
    k_gru<<<dim3(256), dim3(256), 0, stream>>>(gx, gh, hidden, comb, h_out);
    // 3. dsl = h_new @ W_ds^T + b_ds (split-K 4, atomic)
    gemm_t<32,32,32,2,2,4><<<dim3(4,16,4), dim3(256), 0, stream>>>(
        comb, 2*H2_, W_ds, H2_, dsl, H2_, H2_, H2_);
    // 4. attention scores
    k_scores<<<dim3(L_*B_/4), dim3(256), 0, stream>>>(enc, dsl, w_h, att_v, scores);
    // 5. softmax over batch axis
    k_softmax<<<dim3(L_), dim3(64), 0, stream>>>(scores, attn);
    // 6. context
    k_context<<<dim3(B_, 8), dim3(512), 0, stream>>>(enc, attn, comb);
    // 7. p_gen
    k_pgen<<<dim3(B_), dim3(64), 0, stream>>>(comb, input_ids, emb_tab, W_ptr, b_ptr, pgen);
    // 8. hid = comb @ W_oh^T + b_oh (split-K 8, atomic)
    gemm_t<32,32,32,2,2,8><<<dim3(4,4,8), dim3(256), 0, stream>>>(
        comb, 2*H2_, W_oh, 2*H2_, hid, E_, E_, 2*H2_);
    // 9. cooperative: vocab mfma + exp + rsum | scale-write | scatter
    void* args[] = {(void*)&hid, (void*)&W_ov, (void*)&b_ov, (void*)&pgen,
                    (void*)&rsum, (void*)&p_final, (void*)&full_in, (void*)&attn};
    hipLaunchCooperativeKernel((const void*)k_vocab_coop, dim3(391), dim3(256),
                               args, 0, stream);
}

// Round 6
// 144.543 us; speedup vs baseline: 2.4790x; 2.4790x over previous
//
#include <hip/hip_runtime.h>
#include <math.h>

#define B_  128
#define E_  128
#define H2_ 512
#define H3_ 1536
#define L_  512
#define V_  50000
#define VL_ 50512   // V + L

typedef short bf16x8 __attribute__((ext_vector_type(8)));
typedef float f32x4 __attribute__((ext_vector_type(4)));

__device__ __forceinline__ float fast_tanh(float x) {
    float e = __expf(2.f * x);
    return 1.f - 2.f / (e + 1.f);
}
__device__ __forceinline__ float fast_sigmoid(float x) {
    return 1.f / (1.f + __expf(-x));
}
__device__ __forceinline__ short f2bf(float f) {
    unsigned u = __float_as_uint(f);
    u += 0x7fff + ((u >> 16) & 1);        // RNE
    return (short)(u >> 16);
}

// ---------------- init: bias-broadcast split-K targets, zero pad/rsum8 ----------------
// [0,196608) gx=b_ih | [+196608) gh=b_hh | [+65536) dsl=b_ds | [+16384) hid=b_oh |
// [+65536) out pad=0 | [+1024) rsum8=0       total 541696
__global__ void k_init(float* __restrict__ gx, float* __restrict__ gh,
                       float* __restrict__ dsl, float* __restrict__ hid,
                       float* __restrict__ out, float* __restrict__ rsum8,
                       const float* __restrict__ b_ih, const float* __restrict__ b_hh,
                       const float* __restrict__ b_ds, const float* __restrict__ b_oh) {
    int i = blockIdx.x * blockDim.x + threadIdx.x;
    if (i < 196608) { gx[i] = b_ih[i % 1536]; return; }
    i -= 196608;
    if (i < 196608) { gh[i] = b_hh[i % 1536]; return; }
    i -= 196608;
    if (i < 65536)  { dsl[i] = b_ds[i & 511]; return; }
    i -= 65536;
    if (i < 16384)  { hid[i] = b_oh[i & 127]; return; }
    i -= 16384;
    if (i < 65536)  { out[(size_t)(i >> 9) * VL_ + V_ + (i & 511)] = 0.f; return; }
    i -= 65536;
    if (i < 1024)   rsum8[i] = 0.f;
}

// ---------------- gx & gh GEMMs, split-K, one kernel (z: 0-1 gx, 2-5 gh) -------------
__global__ void k_gates(const int* __restrict__ ids, const float* __restrict__ tab,
                        const float* __restrict__ hidden,
                        const float* __restrict__ W_ih, const float* __restrict__ W_hh,
                        float* __restrict__ gx, float* __restrict__ gh) {
    __shared__ float As[32][36];
    __shared__ float Ws[32][36];
    int z = blockIdx.z;
    int which = (z < 2) ? 0 : 1;
    int kbeg  = which ? (z - 2) * 128 : z * 64;
    int kiter = which ? 4 : 2;
    const float* W = which ? W_hh : W_ih;
    int ldw = which ? H2_ : E_;
    float* C = which ? gh : gx;
    int bm = blockIdx.x * 32, bn = blockIdx.y * 32;
    int tid = threadIdx.x;
    int tm0 = (tid / 16) * 2, tn0 = (tid % 16) * 2;
    float acc[2][2] = {};
    for (int it = 0; it < kiter; ++it) {
        int k0 = kbeg + it * 32;
        for (int v = tid; v < 256; v += 256) {
            int m = v >> 3, q = (v & 7) << 2;
            int gm = bm + m;
            const float* arow = which ? (hidden + (size_t)gm * H2_)
                                      : (tab + (size_t)ids[gm] * E_);
            float4 x = *(const float4*)(arow + k0 + q);
            As[q+0][m] = x.x; As[q+1][m] = x.y; As[q+2][m] = x.z; As[q+3][m] = x.w;
        }
        for (int v = tid; v < 256; v += 256) {
            int n = v >> 3, q = (v & 7) << 2;
            float4 x = *(const float4*)(W + (size_t)(bn + n) * ldw + k0 + q);
            Ws[q+0][n] = x.x; Ws[q+1][n] = x.y; Ws[q+2][n] = x.z; Ws[q+3][n] = x.w;
        }
        __syncthreads();
        #pragma unroll
        for (int kk = 0; kk < 32; ++kk) {
            float a0 = As[kk][tm0], a1 = As[kk][tm0+1];
            float w0 = Ws[kk][tn0], w1 = Ws[kk][tn0+1];
            acc[0][0] += a0*w0; acc[0][1] += a0*w1;
            acc[1][0] += a1*w0; acc[1][1] += a1*w1;
        }
        __syncthreads();
    }
    #pragma unroll
    for (int i = 0; i < 2; ++i)
        #pragma unroll
        for (int j = 0; j < 2; ++j)
            atomicAdd(&C[(size_t)(bm+tm0+i) * H3_ + bn+tn0+j], acc[i][j]);
}

// ---------------- generic tiled GEMM (dsl/hid), split-K atomic ----------------
template<int BM, int BN, int BK, int TM, int TN, int SPLITK>
__global__ void gemm_t(const float* __restrict__ A, int lda,
                       const float* __restrict__ W, int ldw,
                       float* __restrict__ C, int ldc,
                       int N, int K) {
    __shared__ float As[BK][BM + 4];
    __shared__ float Ws[BK][BN + 4];
    int bm = blockIdx.x * BM, bn = blockIdx.y * BN;
    int tid = threadIdx.x;
    constexpr int NT = BN / TN;
    int tm0 = (tid / NT) * TM;
    int tn0 = (tid % NT) * TN;
    int kchunk = K / SPLITK;
    int kbeg = blockIdx.z * kchunk;
    float acc[TM][TN] = {};
    for (int k0 = kbeg; k0 < kbeg + kchunk; k0 += BK) {
        #pragma unroll
        for (int v = tid; v < BM * BK / 4; v += 256) {
            int m = v / (BK / 4), q = (v % (BK / 4)) * 4;
            float4 x = *(const float4*)(A + (size_t)(bm + m) * lda + k0 + q);
            As[q+0][m] = x.x; As[q+1][m] = x.y; As[q+2][m] = x.z; As[q+3][m] = x.w;
        }
        #pragma unroll
        for (int v = tid; v < BN * BK / 4; v += 256) {
            int n = v / (BK / 4), q = (v % (BK / 4)) * 4;
            float4 x = *(const float4*)(W + (size_t)(bn + n) * ldw + k0 + q);
            Ws[q+0][n] = x.x; Ws[q+1][n] = x.y; Ws[q+2][n] = x.z; Ws[q+3][n] = x.w;
        }
        __syncthreads();
        #pragma unroll
        for (int kk = 0; kk < BK; ++kk) {
            float a[TM], w[TN];
            #pragma unroll
            for (int i = 0; i < TM; ++i) a[i] = As[kk][tm0 + i];
            #pragma unroll
            for (int j = 0; j < TN; ++j) w[j] = Ws[kk][tn0 + j];
            #pragma unroll
            for (int i = 0; i < TM; ++i)
                #pragma unroll
                for (int j = 0; j < TN; ++j) acc[i][j] += a[i] * w[j];
        }
        __syncthreads();
    }
    #pragma unroll
    for (int i = 0; i < TM; ++i)
        #pragma unroll
        for (int j = 0; j < TN; ++j)
            atomicAdd(&C[(size_t)(bm+tm0+i) * ldc + bn+tn0+j], acc[i][j]);
}

// ---------------- GRU gates (+ zero ctx region) ----------------
__global__ void k_gru(const float* __restrict__ gx, const float* __restrict__ gh,
                      const float* __restrict__ h0,
                      float* __restrict__ comb, float* __restrict__ hout) {
    int idx = blockIdx.x * blockDim.x + threadIdx.x;  // B*H2 = 65536
    int b = idx >> 9, h = idx & 511;
    const float* gxb = gx + b * H3_;
    const float* ghb = gh + b * H3_;
    float xr = gxb[h], xz = gxb[H2_ + h], xn = gxb[2 * H2_ + h];
    float hr = ghb[h], hz = ghb[H2_ + h], hn = ghb[2 * H2_ + h];
    float r = fast_sigmoid(xr + hr);
    float z = fast_sigmoid(xz + hz);
    float n = fast_tanh(xn + r * hn);
    float hv = (1.f - z) * n + z * h0[idx];
    comb[b * (2 * H2_) + h] = hv;
    comb[b * (2 * H2_) + H2_ + h] = 0.f;
    hout[idx] = hv;
}

// ---------------- attention scores: one wave per (l,b) ----------------
__global__ void k_scores(const float* __restrict__ enc, const float* __restrict__ dsl,
                         const float* __restrict__ w_h, const float* __restrict__ att_v,
                         float* __restrict__ scores) {
    int wid = (blockIdx.x << 2) + (threadIdx.x >> 6);
    int lane = threadIdx.x & 63;
    int l = wid >> 7, b = wid & 127;
    const float4* e4 = (const float4*)(enc + ((size_t)(l * B_ + b)) * H2_);
    const float4* d4 = (const float4*)(dsl + b * H2_);
    const float4* w4 = (const float4*)w_h;
    const float4* v4 = (const float4*)att_v;
    float s = 0.f;
    #pragma unroll
    for (int i = 0; i < 2; ++i) {
        int j = lane + (i << 6);
        float4 e = e4[j], d = d4[j], w = w4[j], v = v4[j];
        s += v.x * fast_tanh(w.x * e.x + d.x);
        s += v.y * fast_tanh(w.y * e.y + d.y);
        s += v.z * fast_tanh(w.z * e.z + d.z);
        s += v.w * fast_tanh(w.w * e.w + d.w);
    }
    #pragma unroll
    for (int o = 32; o; o >>= 1) s += __shfl_xor(s, o);
    if (lane == 0) scores[l * B_ + b] = s;
}

// ---------------- softmax over batch axis (per l) ----------------
__global__ void k_softmax(const float* __restrict__ scores, float* __restrict__ attn) {
    int l = blockIdx.x, lane = threadIdx.x;   // 64 threads
    float s0 = scores[l * B_ + lane], s1 = scores[l * B_ + lane + 64];
    float m = fmaxf(s0, s1);
    #pragma unroll
    for (int o = 32; o; o >>= 1) m = fmaxf(m, __shfl_xor(m, o));
    float e0 = __expf(s0 - m), e1 = __expf(s1 - m);
    float t = e0 + e1;
    #pragma unroll
    for (int o = 32; o; o >>= 1) t += __shfl_xor(t, o);
    float inv = 1.f / t;
    attn[l * B_ + lane] = e0 * inv;
    attn[l * B_ + lane + 64] = e1 * inv;
}

// ---------------- context: block (b, l-chunk of 64), 128 threads, float4 ----------------
__global__ void k_context(const float* __restrict__ enc, const float* __restrict__ attn,
                          float* __restrict__ comb) {
    int b = blockIdx.x;
    int l0 = blockIdx.y << 6;
    int tid = threadIdx.x;               // 128 threads, h4 = tid*4
    __shared__ float a_s[64];
    if (tid < 64) a_s[tid] = attn[(l0 + tid) * B_ + b];
    __syncthreads();
    const float4* e = (const float4*)(enc + ((size_t)l0 * B_ + b) * H2_) + tid;
    float4 c = make_float4(0.f, 0.f, 0.f, 0.f);
    #pragma unroll 8
    for (int i = 0; i < 64; ++i) {
        float4 x = e[(size_t)i * (B_ * H2_ / 4)];
        float a = a_s[i];
        c.x += a * x.x; c.y += a * x.y; c.z += a * x.z; c.w += a * x.w;
    }
    float* dst = comb + b * (2 * H2_) + H2_ + tid * 4;
    atomicAdd(dst + 0, c.x); atomicAdd(dst + 1, c.y);
    atomicAdd(dst + 2, c.z); atomicAdd(dst + 3, c.w);
}

// ---------------- p_gen: one wave per b ----------------
__global__ void k_pgen(const float* __restrict__ comb,
                       const int* __restrict__ ids, const float* __restrict__ tab,
                       const float* __restrict__ W_ptr, const float* __restrict__ b_ptr,
                       float* __restrict__ pgen) {
    int b = blockIdx.x, lane = threadIdx.x;  // 64 threads
    float s = 0.f;
    for (int j = lane; j < 2 * H2_; j += 64) s += W_ptr[j] * comb[b * (2 * H2_) + j];
    const float* erow = tab + (size_t)ids[b] * E_;
    for (int j = lane; j < E_; j += 64) s += W_ptr[2 * H2_ + j] * erow[j];
    #pragma unroll
    for (int o = 32; o; o >>= 1) s += __shfl_xor(s, o);
    if (lane == 0) pgen[b] = fast_sigmoid(s + b_ptr[0]);
}

// ---------------- vocab MFMA GEMM: out = exp(hid@Wov^T + bov), rsum8 partials --------
// 256 thr (4 waves); block covers 128 rows x 128 cols; grid 391.
__global__ void k_vocab(const float* __restrict__ hid, const float* __restrict__ Wov,
                        const float* __restrict__ bov, float* __restrict__ out,
                        float* __restrict__ rsum8) {
    __shared__ float sm[4][128];
    int L = threadIdx.x & 63, w = threadIdx.x >> 6;
    int lrow = L & 15, lk = L >> 4;
    int n0 = blockIdx.x * 128 + w * 32;

    bf16x8 bfr[2][4];
    #pragma unroll
    for (int nt = 0; nt < 2; ++nt) {
        int n = n0 + nt * 16 + lrow;
        #pragma unroll
        for (int kk = 0; kk < 4; ++kk) {
            bf16x8 f;
            if (n < V_) {
                const float* p = Wov + (size_t)n * 128 + kk * 32 + lk * 8;
                float4 x = *(const float4*)p, y = *(const float4*)(p + 4);
                f[0]=f2bf(x.x); f[1]=f2bf(x.y); f[2]=f2bf(x.z); f[3]=f2bf(x.w);
                f[4]=f2bf(y.x); f[5]=f2bf(y.y); f[6]=f2bf(y.z); f[7]=f2bf(y.w);
            } else {
                #pragma unroll
                for (int j = 0; j < 8; ++j) f[j] = 0;
            }
            bfr[nt][kk] = f;
        }
    }
    f32x4 acc[8][2] = {};
    #pragma unroll
    for (int mt = 0; mt < 8; ++mt) {
        bf16x8 afr[4];
        #pragma unroll
        for (int kk = 0; kk < 4; ++kk) {
            const float* p = hid + (size_t)(mt * 16 + lrow) * 128 + kk * 32 + lk * 8;
            float4 x = *(const float4*)p, y = *(const float4*)(p + 4);
            bf16x8 f;
            f[0]=f2bf(x.x); f[1]=f2bf(x.y); f[2]=f2bf(x.z); f[3]=f2bf(x.w);
            f[4]=f2bf(y.x); f[5]=f2bf(y.y); f[6]=f2bf(y.z); f[7]=f2bf(y.w);
            afr[kk] = f;
        }
        #pragma unroll
        for (int nt = 0; nt < 2; ++nt)
            #pragma unroll
            for (int kk = 0; kk < 4; ++kk)
                acc[mt][nt] = __builtin_amdgcn_mfma_f32_16x16x32_bf16(
                    afr[kk], bfr[nt][kk], acc[mt][nt], 0, 0, 0);
    }
    // exp epilogue: write exp to out, accumulate row partials
    float bv[2];
    #pragma unroll
    for (int nt = 0; nt < 2; ++nt) {
        int n = n0 + nt * 16 + lrow;
        bv[nt] = (n < V_) ? bov[n] : 0.f;
    }
    float rs[8][4];
    #pragma unroll
    for (int mt = 0; mt < 8; ++mt) {
        #pragma unroll
        for (int r = 0; r < 4; ++r) rs[mt][r] = 0.f;
        #pragma unroll
        for (int nt = 0; nt < 2; ++nt) {
            int n = n0 + nt * 16 + lrow;
            if (n < V_) {
                #pragma unroll
                for (int r = 0; r < 4; ++r) {
                    int row = mt * 16 + lk * 4 + r;
                    float e = __expf(acc[mt][nt][r] + bv[nt]);
                    out[(size_t)row * VL_ + n] = e;
                    rs[mt][r] += e;
                }
            }
        }
    }
    // reduce across 16 lanes sharing each row
    #pragma unroll
    for (int o = 1; o < 16; o <<= 1)
        #pragma unroll
        for (int mt = 0; mt < 8; ++mt)
            #pragma unroll
            for (int r = 0; r < 4; ++r) rs[mt][r] += __shfl_xor(rs[mt][r], o);
    if (lrow == 0) {
        #pragma unroll
        for (int mt = 0; mt < 8; ++mt)
            #pragma unroll
            for (int r = 0; r < 4; ++r)
                sm[w][mt * 16 + lk * 4 + r] = rs[mt][r];
    }
    __syncthreads();
    if (threadIdx.x < 128) {
        float p = sm[0][threadIdx.x] + sm[1][threadIdx.x]
                + sm[2][threadIdx.x] + sm[3][threadIdx.x];
        atomicAdd(&rsum8[(blockIdx.x & 7) * 128 + threadIdx.x], p);
    }
}

// ---------------- finalize: scale row chunk by pgen/rsum ----------------
__global__ void k_final(float* __restrict__ out, const float* __restrict__ pgen,
                        const float* __restrict__ rsum8) {
    int b = blockIdx.y, chunk = blockIdx.x, tid = threadIdx.x;
    __shared__ float sc;
    if (tid == 0) {
        float s = 0.f;
        #pragma unroll
        for (int j = 0; j < 8; ++j) s += rsum8[j * 128 + b];
        sc = pgen[b] / s;
    }
    __syncthreads();
    int j = chunk * 256 + tid;
    if (j < V_ / 4) {
        float4* p = (float4*)(out + (size_t)b * VL_) + j;
        float4 x = *p;
        x.x *= sc; x.y *= sc; x.z *= sc; x.w *= sc;
        *p = x;
    }
}

// ---------------- scatter copy distribution ----------------
__global__ void k_scatter(float* __restrict__ out, const int* __restrict__ full_input,
                          const float* __restrict__ attn, const float* __restrict__ pgen) {
    int idx = blockIdx.x * blockDim.x + threadIdx.x;  // L*B = 65536
    int b = idx & 127;
    int tok = full_input[idx];
    atomicAdd(&out[(size_t)b * VL_ + tok], (1.f - pgen[b]) * attn[idx]);
}

extern "C" void kernel_launch(void* const* d_in, const int* in_sizes, int n_in,
                              void* d_out, int out_size, void* d_ws, size_t ws_size,
                              hipStream_t stream) {
    const int*   input_ids = (const int*)d_in[0];
    const float* hidden    = (const float*)d_in[1];
    const float* enc       = (const float*)d_in[2];
    const int*   full_in   = (const int*)d_in[3];
    const float* emb_tab   = (const float*)d_in[4];
    const float* W_ih      = (const float*)d_in[5];
    const float* W_hh      = (const float*)d_in[6];
    const float* b_ih      = (const float*)d_in[7];
    const float* b_hh      = (const float*)d_in[8];
    const float* W_ds      = (const float*)d_in[9];
    const float* b_ds      = (const float*)d_in[10];
    const float* w_h       = (const float*)d_in[11];
    const float* att_v     = (const float*)d_in[12];
    const float* W_oh      = (const float*)d_in[13];
    const float* b_oh      = (const float*)d_in[14];
    const float* W_ov      = (const float*)d_in[15];
    const float* b_ov      = (const float*)d_in[16];
    const float* W_ptr     = (const float*)d_in[17];
    const float* b_ptr     = (const float*)d_in[18];

    float* out = (float*)d_out;
    float* p_final = out;                                  // [B, VL]
    float* h_out   = out + (size_t)B_ * VL_;               // [B, H2]
    float* attn    = out + (size_t)B_ * VL_ + B_ * H2_;    // [L, B]

    float* ws = (float*)d_ws;
    float* gx     = ws;            // 196608
    float* gh     = gx + 196608;   // 196608
    float* comb   = gh + 196608;   // 131072  [B, 2*H2]: h_new | context
    float* dsl    = comb + 131072; // 65536
    float* scores = dsl + 65536;   // 65536
    float* hid    = scores + 65536;// 16384
    float* pgen   = hid + 16384;   // 128
    float* rsum8  = pgen + 128;    // 1024

    // 0. init bias targets / zero pad & rsum8
    k_init<<<dim3(2116), dim3(256), 0, stream>>>(gx, gh, dsl, hid, out, rsum8,
                                                 b_ih, b_hh, b_ds, b_oh);
    // 1. gx & gh GEMMs (split-K, atomic)
    k_gates<<<dim3(4,48,6), dim3(256), 0, stream>>>(input_ids, emb_tab, hidden,
                                                    W_ih, W_hh, gx, gh);
    // 2. GRU -> h_new (+ zero ctx region)
    k_gru<<<dim3(256), dim3(256), 0, stream>>>(gx, gh, hidden, comb, h_out);
    // 3. dsl = h_new @ W_ds^T + b_ds (split-K 4)
    gemm_t<32,32,32,2,2,4><<<dim3(4,16,4), dim3(256), 0, stream>>>(
        comb, 2*H2_, W_ds, H2_, dsl, H2_, H2_, H2_);
    // 4. attention scores
    k_scores<<<dim3(L_*B_/4), dim3(256), 0, stream>>>(enc, dsl, w_h, att_v, scores);
    // 5. softmax over batch axis
    k_softmax<<<dim3(L_), dim3(64), 0, stream>>>(scores, attn);
    // 6. context (float4)
    k_context<<<dim3(B_, 8), dim3(128), 0, stream>>>(enc, attn, comb);
    // 7. p_gen
    k_pgen<<<dim3(B_), dim3(64), 0, stream>>>(comb, input_ids, emb_tab, W_ptr, b_ptr, pgen);
    // 8. hid = comb @ W_oh^T + b_oh (split-K 8)
    gemm_t<32,32,32,2,2,8><<<dim3(4,4,8), dim3(256), 0, stream>>>(
        comb, 2*H2_, W_oh, 2*H2_, hid, E_, E_, 2*H2_);
    // 9. vocab MFMA: out = exp(logits), rsum8 partials
    k_vocab<<<dim3(391), dim3(256), 0, stream>>>(hid, W_ov, b_ov, p_final, rsum8);
    // 10. scale by pgen/rsum
    k_final<<<dim3(49, 128), dim3(256), 0, stream>>>(p_final, pgen, rsum8);
    // 11. scatter
    k_scatter<<<dim3(L_*B_/256), dim3(256), 0, stream>>>(p_final, full_in, attn, pgen);
}